// Round 12
// baseline (267.085 us; speedup 1.0000x reference)
//
#include <hip/hip_runtime.h>
#include <hip/hip_bf16.h>
#include <cstdint>

#define EMB 1024
#define HEADS 16
#define HD 64
#define BATCH 4
#define SEQ 2048
#define BT (BATCH*SEQ)                 // 8192 tokens
#define LNEPS 1e-5f
#define QK_SCALE 0.17677669529663687f  // 1024^-0.25
#define LOG2E 1.4426950408889634f

typedef __bf16 bf16;
typedef __bf16 bf16x8 __attribute__((ext_vector_type(8)));
typedef __bf16 bf16x4 __attribute__((ext_vector_type(4)));
typedef float  f32x4  __attribute__((ext_vector_type(4)));
typedef short  s16x4  __attribute__((ext_vector_type(4)));

typedef const __attribute__((address_space(1))) void* gas_ptr;
typedef __attribute__((address_space(3))) void*       las_ptr;

__device__ __forceinline__ void gld_lds16(const void* g, void* l) {
  __builtin_amdgcn_global_load_lds((gas_ptr)g, (las_ptr)l, 16, 0, 0);
}

// PV matmul: 16x16x16 bf16 MFMA (C-layout of S^T == B-layout of this shape).
__device__ __forceinline__ f32x4 mfma_pv(bf16x4 a, bf16x4 b, f32x4 c) {
  return __builtin_amdgcn_mfma_f32_16x16x16bf16_1k(
      __builtin_bit_cast(s16x4, a), __builtin_bit_cast(s16x4, b), c, 0, 0, 0);
}

// ---------------- fused fp32->bf16 conversions (x + 4 weight mats) ----------------
// blocks [0,8192): x (2M float4); blocks [8192,12288): W4 (1M float4).
__global__ void cvt_all(const float* __restrict__ x,
                        const float* __restrict__ w0, const float* __restrict__ w1,
                        const float* __restrict__ w2, const float* __restrict__ w3,
                        bf16* __restrict__ xb, bf16* __restrict__ wb) {
  const int bid = blockIdx.x;
  if (bid < 8192) {
    int i = bid * 256 + threadIdx.x;           // over BT*EMB/4 float4s
    float4 f = reinterpret_cast<const float4*>(x)[i];
    bf16x4 o = { (bf16)f.x, (bf16)f.y, (bf16)f.z, (bf16)f.w };
    reinterpret_cast<bf16x4*>(xb)[i] = o;
  } else {
    int i = (bid - 8192) * 256 + threadIdx.x;  // over 4*EMB*EMB/4 float4s
    int sel = i >> 18;
    int j = i & 262143;
    const float* s = (sel == 0) ? w0 : (sel == 1) ? w1 : (sel == 2) ? w2 : w3;
    float4 f = reinterpret_cast<const float4*>(s)[j];
    bf16x4 o = { (bf16)f.x, (bf16)f.y, (bf16)f.z, (bf16)f.w };
    reinterpret_cast<bf16x4*>(wb)[i] = o;
  }
}

// ======== BK=32 dbuf GEMM core (kqv best config, r10/r11 measured) ========
// One barrier per K-tile, prefetch issued a compute-phase before its drain.
// Rows 64B = 4 chunks of 16B; swizzle chunk ^= (row>>1)&3 on BOTH the
// pre-swizzled global source and the fragment read (rule 21) -> 2-way max.
#define GEMM_DBUF_LOOP32(A_, B_, K_)                                          \
  f32x4 zero4 = {0.f, 0.f, 0.f, 0.f};                                         \
  f32x4 acc[4][4];                                                            \
  _Pragma("unroll")                                                           \
  for (int i = 0; i < 4; i++)                                                 \
    _Pragma("unroll")                                                         \
    for (int j = 0; j < 4; j++) acc[i][j] = zero4;                            \
  const int u0_ = t * 8, u1_ = t * 8 + 2048;                                  \
  const int sr0 = u0_ >> 5, sc0 = ((t & 3) ^ ((sr0 >> 1) & 3));               \
  const int sr1 = u1_ >> 5, sc1 = ((t & 3) ^ ((sr1 >> 1) & 3));               \
  const int nt_ = K_ / 32;                                                    \
  {                                                                           \
    gld_lds16(A_ + (size_t)(m0 + sr0) * K_ + sc0 * 8, &As[0][u0_]);           \
    gld_lds16(A_ + (size_t)(m0 + sr1) * K_ + sc1 * 8, &As[0][u1_]);           \
    gld_lds16(B_ + (size_t)(n0 + sr0) * K_ + sc0 * 8, &Bs[0][u0_]);           \
    gld_lds16(B_ + (size_t)(n0 + sr1) * K_ + sc1 * 8, &Bs[0][u1_]);           \
  }                                                                           \
  for (int kt = 0; kt < nt_; ++kt) {                                          \
    const int buf = kt & 1;                                                   \
    __syncthreads();                                                          \
    if (kt + 1 < nt_) {                                                       \
      const int k0 = (kt + 1) * 32;                                           \
      gld_lds16(A_ + (size_t)(m0 + sr0) * K_ + k0 + sc0 * 8, &As[buf^1][u0_]);\
      gld_lds16(A_ + (size_t)(m0 + sr1) * K_ + k0 + sc1 * 8, &As[buf^1][u1_]);\
      gld_lds16(B_ + (size_t)(n0 + sr0) * K_ + k0 + sc0 * 8, &Bs[buf^1][u0_]);\
      gld_lds16(B_ + (size_t)(n0 + sr1) * K_ + k0 + sc1 * 8, &Bs[buf^1][u1_]);\
    }                                                                         \
    bf16x8 af[4], bfr[4];                                                     \
    _Pragma("unroll")                                                         \
    for (int mi = 0; mi < 4; mi++) {                                          \
      const int row = wm + mi * 16 + ln;                                      \
      af[mi] = *reinterpret_cast<const bf16x8*>(                              \
          &As[buf][row * 32 + ((q ^ ((row >> 1) & 3))) * 8]);                 \
    }                                                                         \
    _Pragma("unroll")                                                         \
    for (int ni = 0; ni < 4; ni++) {                                          \
      const int row = wn + ni * 16 + ln;                                      \
      bfr[ni] = *reinterpret_cast<const bf16x8*>(                             \
          &Bs[buf][row * 32 + ((q ^ ((row >> 1) & 3))) * 8]);                 \
    }                                                                         \
    _Pragma("unroll")                                                         \
    for (int mi = 0; mi < 4; mi++)                                            \
      _Pragma("unroll")                                                       \
      for (int ni = 0; ni < 4; ni++)                                          \
        acc[mi][ni] = __builtin_amdgcn_mfma_f32_16x16x32_bf16(                \
            af[mi], bfr[ni], acc[mi][ni], 0, 0, 0);                           \
  }

// ---------------- fused QKV GEMM + per-head LN(K,Q) + V transpose ----------------
// C[8192][3072] = xb * wb^T; C never hits memory:
//   cols [0,1024):   K-proj -> per-head LN (scale QK_SCALE*LOG2E) -> kn [bh][t][64]
//   cols [1024,2048) Q-proj -> per-head LN (scale QK_SCALE)       -> qn [bh][t][64]
//   cols [2048,3072) V-proj ->                                       vt [bh][64][2048]
// XCD-affine remap (grid 24x64): per-XCD resident panels ~4MB = its L2.
__global__ __launch_bounds__(256, 2) void gemm_kqv(
    const bf16* __restrict__ A, const bf16* __restrict__ Bm,
    bf16* __restrict__ kn, bf16* __restrict__ qn, bf16* __restrict__ vt,
    const float* __restrict__ kg, const float* __restrict__ kb,
    const float* __restrict__ qg, const float* __restrict__ qb)
{
  __shared__ __align__(16) bf16 As[2][128 * 32];
  __shared__ __align__(16) bf16 Bs[2][128 * 32];

  const int t    = threadIdx.x;
  const int lane = t & 63;
  const int wave = t >> 6;
  const int q    = lane >> 4;
  const int ln   = lane & 15;

  const int lid = (int)blockIdx.y * (int)gridDim.x + (int)blockIdx.x;
  const int xcd = lid & 7;
  const int nn  = lid >> 3;
  const int bxr = nn >> 3;                 // [0, 24)
  const int byr = (xcd << 3) | (nn & 7);   // [0, 64)
  const int m0  = byr * 128;
  const int n0  = bxr * 128;

  const int wm = (wave >> 1) * 64;
  const int wn = (wave & 1) * 64;

  GEMM_DBUF_LOOP32(A, Bm, EMB)

  // ---- epilogue (unchanged from round 6, verified) ----
  const int sec = n0 >> 10;                 // 0=K, 1=Q, 2=V
  const int cb  = (n0 & 1023) + wn;         // col within projection
  const int h   = cb >> 6;                  // head
  const int R0  = m0 + wm;

  if (sec == 2) {
    // V: write transposed [bh][d][t]; lane holds 4 consecutive t at fixed d
#pragma unroll
    for (int mi = 0; mi < 4; mi++) {
      const int R = R0 + mi * 16 + q * 4;
      const int b = R >> 11, tt = R & 2047;
#pragma unroll
      for (int ni = 0; ni < 4; ni++) {
        const int d = ni * 16 + ln;
        bf16x4 o4 = { (bf16)acc[mi][ni][0], (bf16)acc[mi][ni][1],
                      (bf16)acc[mi][ni][2], (bf16)acc[mi][ni][3] };
        *reinterpret_cast<bf16x4*>(
            &vt[((size_t)(b * HEADS + h) * HD + d) * SEQ + tt]) = o4;
      }
    }
  } else {
    const float scale = sec ? QK_SCALE : (QK_SCALE * LOG2E);
    const float* gp = sec ? qg : kg;
    const float* bp = sec ? qb : kb;
    bf16* outp = sec ? qn : kn;
    float gv[4], bv[4];
#pragma unroll
    for (int ni = 0; ni < 4; ni++) {
      gv[ni] = gp[ni * 16 + ln];
      bv[ni] = bp[ni * 16 + ln] * scale;
    }
#pragma unroll
    for (int mi = 0; mi < 4; mi++) {
#pragma unroll
      for (int r = 0; r < 4; r++) {
        const float x0 = acc[mi][0][r], x1 = acc[mi][1][r];
        const float x2 = acc[mi][2][r], x3 = acc[mi][3][r];
        float s  = (x0 + x1) + (x2 + x3);
        float s2 = (x0 * x0 + x1 * x1) + (x2 * x2 + x3 * x3);
#pragma unroll
        for (int mm = 1; mm < 16; mm <<= 1) {
          s  += __shfl_xor(s,  mm, 64);
          s2 += __shfl_xor(s2, mm, 64);
        }
        const float mean = s * (1.f / 64.f);
        const float rs = rsqrtf(s2 * (1.f / 64.f) - mean * mean + LNEPS) * scale;
        const int R = R0 + mi * 16 + q * 4 + r;
        const int b = R >> 11, tt = R & 2047;
        const size_t o = ((size_t)(b * HEADS + h) * SEQ + tt) * HD + ln;
#pragma unroll
        for (int ni = 0; ni < 4; ni++)
          outp[o + ni * 16] = (bf16)((acc[mi][ni][r] - mean) * rs * gv[ni] + bv[ni]);
      }
    }
  }
}

// ---------------- output-proj GEMM: out[M][N] = A[M][K] * B[N][K]^T + bias ----------------
// ROUND-12 CHANGE: grid is fixed at 512 blocks (M/128 x N/128) = 2 blocks/CU —
// residency-limited. With 4 waves that was 8 waves/CU (25% occ): every barrier
// drain stalled a nearly-empty CU (ledger says ~60-70us, ~230 TF). Fix: SAME
// 128x128 tile, SAME BK=64 dbuf 1-barrier loop + row&7 swizzle (r8-verified),
// but 512 threads / 8 waves -> per-wave 64x32 (acc[4][2]) -> 16 waves/CU, 2x
// latency hiding at identical LDS (64KB) and barrier count (16).
__global__ __launch_bounds__(512, 4) void gemm_out(
    const bf16* __restrict__ A, const bf16* __restrict__ Bm,
    float* __restrict__ Cf, const float* __restrict__ bias, int N)
{
  __shared__ __align__(16) bf16 As[2][128 * 64];
  __shared__ __align__(16) bf16 Bs[2][128 * 64];

  const int t    = threadIdx.x;            // 0..511
  const int lane = t & 63;
  const int wave = t >> 6;                 // 0..7
  const int q    = lane >> 4;
  const int ln   = lane & 15;

  const int lid = (int)blockIdx.y * (int)gridDim.x + (int)blockIdx.x;
  const int xcd = lid & 7;
  const int nn  = lid >> 3;
  const int bxr = nn >> 3;                 // [0, 8)
  const int byr = (xcd << 3) | (nn & 7);   // [0, 64)
  const int m0  = byr * 128;
  const int n0  = bxr * 128;

  const int wm = (wave >> 2) * 64;         // {0, 64}
  const int wn = (wave & 3) * 32;          // {0, 32, 64, 96}

  const int K = EMB;
  f32x4 zero4 = {0.f, 0.f, 0.f, 0.f};
  f32x4 acc[4][2];
#pragma unroll
  for (int i = 0; i < 4; i++)
#pragma unroll
    for (int j = 0; j < 2; j++) acc[i][j] = zero4;

  // staging: 2 chunks per tensor per thread; 16KB/tensor/buf = 1024 chunks.
  // chunk u (elements): row = u>>6 (64 elem = 128B rows), col = (u>>3)&7,
  // pre-swizzled source col ^= row&7 (matches fragment-read swizzle).
  const int uA0 = t * 8, uA1 = t * 8 + 4096;
  const int r0_ = uA0 >> 6, c0_ = ((uA0 >> 3) & 7) ^ (r0_ & 7);
  const int r1_ = uA1 >> 6, c1_ = ((uA1 >> 3) & 7) ^ (r1_ & 7);

  {                                        // prologue: stage kt=0 into buf 0
    gld_lds16(A  + (size_t)(m0 + r0_) * K + c0_ * 8, &As[0][uA0]);
    gld_lds16(A  + (size_t)(m0 + r1_) * K + c1_ * 8, &As[0][uA1]);
    gld_lds16(Bm + (size_t)(n0 + r0_) * K + c0_ * 8, &Bs[0][uA0]);
    gld_lds16(Bm + (size_t)(n0 + r1_) * K + c1_ * 8, &Bs[0][uA1]);
  }

  for (int kt = 0; kt < K / 64; ++kt) {
    const int buf = kt & 1;
    __syncthreads();                       // buf staged; buf^1 reads drained
    if (kt + 1 < K / 64) {                 // prefetch next K-tile
      const int k0 = (kt + 1) * 64;
      gld_lds16(A  + (size_t)(m0 + r0_) * K + k0 + c0_ * 8, &As[buf ^ 1][uA0]);
      gld_lds16(A  + (size_t)(m0 + r1_) * K + k0 + c1_ * 8, &As[buf ^ 1][uA1]);
      gld_lds16(Bm + (size_t)(n0 + r0_) * K + k0 + c0_ * 8, &Bs[buf ^ 1][uA0]);
      gld_lds16(Bm + (size_t)(n0 + r1_) * K + k0 + c1_ * 8, &Bs[buf ^ 1][uA1]);
    }
#pragma unroll
    for (int ks = 0; ks < 2; ++ks) {
      bf16x8 af[4], bfr[2];
#pragma unroll
      for (int mi = 0; mi < 4; mi++) {
        const int row = wm + mi * 16 + ln;
        af[mi] = *reinterpret_cast<const bf16x8*>(
            &As[buf][row * 64 + ((ks * 4 + q) ^ (row & 7)) * 8]);
      }
#pragma unroll
      for (int ni = 0; ni < 2; ni++) {
        const int row = wn + ni * 16 + ln;
        bfr[ni] = *reinterpret_cast<const bf16x8*>(
            &Bs[buf][row * 64 + ((ks * 4 + q) ^ (row & 7)) * 8]);
      }
#pragma unroll
      for (int mi = 0; mi < 4; mi++)
#pragma unroll
        for (int ni = 0; ni < 2; ni++)
          acc[mi][ni] = __builtin_amdgcn_mfma_f32_16x16x32_bf16(
              af[mi], bfr[ni], acc[mi][ni], 0, 0, 0);
    }
  }

#pragma unroll
  for (int mi = 0; mi < 4; mi++) {
#pragma unroll
    for (int ni = 0; ni < 2; ni++) {
#pragma unroll
      for (int r = 0; r < 4; r++) {
        int row = m0 + wm + mi * 16 + q * 4 + r;
        int col = n0 + wn + ni * 16 + ln;
        Cf[(size_t)row * N + col] = acc[mi][ni][r] + bias[col];
      }
    }
  }
}

// ---------------- flash attention (causal), S^T form, paired tiles + dbuf ----------------
// 1-D grid of 1024 blocks, XCD-affine decode: xcd=id&7, bx=(id>>3)&15,
// bh=(id>>7)*8+xcd -> all 16 blocks of a bh on ONE XCD (its L2 holds 8 bhs'
// K/V; FETCH 255->25MB, round 3). Pass pairing (bx then 31-bx): uniform 33
// j-steps per block. j-tile 64, double-buffered K/V (32KB LDS, 4 blocks/CU),
// one barrier per tile, prefetch issued before compute. Swizzles: 16B-chunk
// XOR (row&7), both-sides involution -> 2-way max on reads (free).
__global__ __launch_bounds__(256, 4) void attn(
    const bf16* __restrict__ Qn, const bf16* __restrict__ Kn, const bf16* __restrict__ Vt,
    bf16* __restrict__ O)
{
  __shared__ __align__(16) bf16 Ks[2][64 * 64];   // [j][d]
  __shared__ __align__(16) bf16 Vs[2][64 * 64];   // [d][j]

  const int id = blockIdx.x;
  const int bh = ((id >> 7) << 3) | (id & 7);     // same-bh blocks share an XCD
  const int bxi = (id >> 3) & 15;
  const int t = threadIdx.x, wave = t >> 6, lane = t & 63;
  const int q = lane >> 4, ln = lane & 15;
  const int b = bh >> 4, h = bh & 15;

  // staging: 2 chunks of 16B per tensor per thread (u0, u0+2048 elems)
  const int u0 = t * 8, u1 = t * 8 + 2048;
  const int kr0 = u0 >> 6, kc0 = ((u0 >> 3) & 7) ^ (kr0 & 7);
  const int kr1 = u1 >> 6, kc1 = ((u1 >> 3) & 7) ^ (kr1 & 7);
  const int vd0 = u0 >> 6, vc0 = ((u0 >> 3) & 7) ^ (vd0 & 7);
  const int vd1 = u1 >> 6, vc1 = ((u1 >> 3) & 7) ^ (vd1 & 7);
  const bf16* Kb = Kn + (size_t)bh * SEQ * HD;
  const bf16* Vb = Vt + (size_t)bh * HD * SEQ;

  f32x4 zero4 = {0.f, 0.f, 0.f, 0.f};

  for (int pass = 0; pass < 2; ++pass) {
    const int itile = pass ? (31 - bxi) : bxi;
    const int qbase = itile * 64 + wave * 16;

    // Q fragments (B-operand of S^T mfma): Q[i=qbase+ln][d=ks*32+q*8 ..+8]
    const bf16* qp = Qn + ((size_t)bh * SEQ + qbase + ln) * HD + q * 8;
    bf16x8 qf0 = *reinterpret_cast<const bf16x8*>(qp);
    bf16x8 qf1 = *reinterpret_cast<const bf16x8*>(qp + 32);

    float lrow = 0.f;
    f32x4 oacc[4];                          // [md] tiles of O^T[d][i]
#pragma unroll
    for (int md = 0; md < 4; md++) oacc[md] = zero4;

    const int nj = itile + 1;               // 64-j tiles covering 0..i0+63

    __syncthreads();                        // prior pass/iter reads done before overwrite
    {                                       // prologue: stage jt=0 into buf 0
      gld_lds16(Kb + (size_t)kr0 * HD + kc0 * 8, &Ks[0][u0]);
      gld_lds16(Kb + (size_t)kr1 * HD + kc1 * 8, &Ks[0][u1]);
      gld_lds16(Vb + (size_t)vd0 * SEQ + vc0 * 8, &Vs[0][u0]);
      gld_lds16(Vb + (size_t)vd1 * SEQ + vc1 * 8, &Vs[0][u1]);
    }

    for (int jt = 0; jt < nj; ++jt) {
      const int buf = jt & 1;
      const int j0 = jt * 64;
      __syncthreads();                      // buf staged & visible; buf^1 reads drained
      if (jt + 1 < nj) {                    // prefetch next tile into other buffer
        const int jn = j0 + 64;
        gld_lds16(Kb + (size_t)(jn + kr0) * HD + kc0 * 8, &Ks[buf ^ 1][u0]);
        gld_lds16(Kb + (size_t)(jn + kr1) * HD + kc1 * 8, &Ks[buf ^ 1][u1]);
        gld_lds16(Vb + (size_t)vd0 * SEQ + jn + vc0 * 8, &Vs[buf ^ 1][u0]);
        gld_lds16(Vb + (size_t)vd1 * SEQ + jn + vc1 * 8, &Vs[buf ^ 1][u1]);
      }

#pragma unroll
      for (int jb = 0; jb < 4; ++jb) {
        const int jslab = j0 + jb * 16;
        if (jslab <= qbase + 15) {          // slab has unmasked elems for this wave
          const int rowj = jb * 16 + ln;
          bf16x8 kf0 = *reinterpret_cast<const bf16x8*>(
              &Ks[buf][rowj * 64 + ((q)     ^ (rowj & 7)) * 8]);
          bf16x8 kf1 = *reinterpret_cast<const bf16x8*>(
              &Ks[buf][rowj * 64 + ((4 + q) ^ (rowj & 7)) * 8]);
          f32x4 z = zero4;
          z = __builtin_amdgcn_mfma_f32_16x16x32_bf16(kf0, qf0, z, 0, 0, 0);
          z = __builtin_amdgcn_mfma_f32_16x16x32_bf16(kf1, qf1, z, 0, 0, 0);
          // z[r] = S^T[j = jslab+q*4+r][i = qbase+ln]
          if (jslab + 15 > qbase) {         // partial slab: mask
#pragma unroll
            for (int r = 0; r < 4; r++) {
              int jj = jslab + q * 4 + r;
              int ii = qbase + ln;
              if (jj > ii) z[r] = -1.0e30f;
            }
          }
          // fixed-max softmax (|s*log2e| <= 2.9 after per-head LN): p = 2^s
          float p0 = exp2f(z[0]), p1 = exp2f(z[1]), p2 = exp2f(z[2]), p3 = exp2f(z[3]);
          lrow += (p0 + p1) + (p2 + p3);
          bf16x4 pk = { (bf16)p0, (bf16)p1, (bf16)p2, (bf16)p3 };   // B-frag (k=j, n=i)

          // O^T += V^T * P^T for this 16-j slab
#pragma unroll
          for (int md = 0; md < 4; md++) {
            const int rowd = md * 16 + ln;
            const bf16* vp = &Vs[buf][rowd * 64 +
                (((jb * 2 + (q >> 1)) ^ (rowd & 7)) * 8) + (q & 1) * 4];
            bf16x4 vf = *reinterpret_cast<const bf16x4*>(vp);
            oacc[md] = mfma_pv(vf, pk, oacc[md]);
          }
        }
      }
    }

    // epilogue: reduce l over the 4 quads holding each column i, normalize, store
    float s = lrow;
    s += __shfl_xor(s, 16, 64);
    s += __shfl_xor(s, 32, 64);
    const float inv = 1.f / s;
    const int row = qbase + ln;
#pragma unroll
    for (int md = 0; md < 4; md++) {
      bf16x4 o4 = { (bf16)(oacc[md][0] * inv), (bf16)(oacc[md][1] * inv),
                    (bf16)(oacc[md][2] * inv), (bf16)(oacc[md][3] * inv) };
      int col = h * HD + md * 16 + q * 4;    // 4 consecutive d
      *reinterpret_cast<bf16x4*>(&O[(size_t)(b * SEQ + row) * EMB + col]) = o4;
    }
  }
}

// ---------------- launch ----------------
extern "C" void kernel_launch(void* const* d_in, const int* in_sizes, int n_in,
                              void* d_out, int out_size, void* d_ws, size_t ws_size,
                              hipStream_t stream)
{
  const float* x   = (const float*)d_in[0];
  const float* Wk  = (const float*)d_in[1];
  const float* Wq  = (const float*)d_in[2];
  const float* Wv  = (const float*)d_in[3];
  const float* Wo  = (const float*)d_in[4];
  const float* bo  = (const float*)d_in[5];
  const float* klg = (const float*)d_in[6];
  const float* klb = (const float*)d_in[7];
  const float* qlg = (const float*)d_in[8];
  const float* qlb = (const float*)d_in[9];
  float* out = (float*)d_out;

  char* ws = (char*)d_ws;
  const size_t OFF_XB  = 0;
  const size_t OFF_WB  = OFF_XB  + (size_t)BT * EMB * 2;
  const size_t OFF_KQV = OFF_WB  + (size_t)4 * EMB * EMB * 2;
  const size_t OFF_KN  = OFF_KQV + (size_t)BT * 3 * EMB * 2;
  const size_t OFF_QN  = OFF_KN  + (size_t)BT * EMB * 2;
  const size_t OFF_VT  = OFF_QN  + (size_t)BT * EMB * 2;
  const size_t OFF_END = OFF_VT  + (size_t)BT * EMB * 2;
  if (ws_size < OFF_END) return;

  bf16* xb   = (bf16*)(ws + OFF_XB);
  bf16* wb   = (bf16*)(ws + OFF_WB);
  bf16* kn   = (bf16*)(ws + OFF_KN);
  bf16* qn   = (bf16*)(ws + OFF_QN);
  bf16* vt   = (bf16*)(ws + OFF_VT);
  bf16* ob   = (bf16*)(ws + OFF_KQV);    // attn output (KQV region unused otherwise)

  cvt_all<<<12288, 256, 0, stream>>>(x, Wk, Wq, Wv, Wo, xb, wb);

  gemm_kqv<<<dim3(3 * EMB / 128, BT / 128), 256, 0, stream>>>(
      xb, wb, kn, qn, vt, klg, klb, qlg, qlb);

  attn<<<dim3(16 * BATCH * HEADS), 256, 0, stream>>>(qn, kn, vt, ob);

  gemm_out<<<dim3(EMB / 128, BT / 128), 512, 0, stream>>>(
      ob, wb + (size_t)3 * EMB * EMB, out, bo, EMB);
}

// Round 13
// 259.943 us; speedup vs baseline: 1.0275x; 1.0275x over previous
//
#include <hip/hip_runtime.h>
#include <hip/hip_bf16.h>
#include <cstdint>

#define EMB 1024
#define HEADS 16
#define HD 64
#define BATCH 4
#define SEQ 2048
#define BT (BATCH*SEQ)                 // 8192 tokens
#define LNEPS 1e-5f
#define QK_SCALE 0.17677669529663687f  // 1024^-0.25
#define LOG2E 1.4426950408889634f

typedef __bf16 bf16;
typedef __bf16 bf16x8 __attribute__((ext_vector_type(8)));
typedef __bf16 bf16x4 __attribute__((ext_vector_type(4)));
typedef float  f32x4  __attribute__((ext_vector_type(4)));
typedef short  s16x4  __attribute__((ext_vector_type(4)));

typedef const __attribute__((address_space(1))) void* gas_ptr;
typedef __attribute__((address_space(3))) void*       las_ptr;

__device__ __forceinline__ void gld_lds16(const void* g, void* l) {
  __builtin_amdgcn_global_load_lds((gas_ptr)g, (las_ptr)l, 16, 0, 0);
}

// PV matmul: 16x16x16 bf16 MFMA (C-layout of S^T == B-layout of this shape).
__device__ __forceinline__ f32x4 mfma_pv(bf16x4 a, bf16x4 b, f32x4 c) {
  return __builtin_amdgcn_mfma_f32_16x16x16bf16_1k(
      __builtin_bit_cast(s16x4, a), __builtin_bit_cast(s16x4, b), c, 0, 0, 0);
}

// ---------------- fused fp32->bf16 conversions (x + 4 weight mats) ----------------
// blocks [0,8192): x (2M float4); blocks [8192,12288): W4 (1M float4).
__global__ void cvt_all(const float* __restrict__ x,
                        const float* __restrict__ w0, const float* __restrict__ w1,
                        const float* __restrict__ w2, const float* __restrict__ w3,
                        bf16* __restrict__ xb, bf16* __restrict__ wb) {
  const int bid = blockIdx.x;
  if (bid < 8192) {
    int i = bid * 256 + threadIdx.x;           // over BT*EMB/4 float4s
    float4 f = reinterpret_cast<const float4*>(x)[i];
    bf16x4 o = { (bf16)f.x, (bf16)f.y, (bf16)f.z, (bf16)f.w };
    reinterpret_cast<bf16x4*>(xb)[i] = o;
  } else {
    int i = (bid - 8192) * 256 + threadIdx.x;  // over 4*EMB*EMB/4 float4s
    int sel = i >> 18;
    int j = i & 262143;
    const float* s = (sel == 0) ? w0 : (sel == 1) ? w1 : (sel == 2) ? w2 : w3;
    float4 f = reinterpret_cast<const float4*>(s)[j];
    bf16x4 o = { (bf16)f.x, (bf16)f.y, (bf16)f.z, (bf16)f.w };
    reinterpret_cast<bf16x4*>(wb)[i] = o;
  }
}

// ======== BK=32 dbuf GEMM core (kqv best config, r10/r11 measured) ========
// One barrier per K-tile, prefetch issued a compute-phase before its drain.
// Rows 64B = 4 chunks of 16B; swizzle chunk ^= (row>>1)&3 on BOTH the
// pre-swizzled global source and the fragment read (rule 21) -> 2-way max.
#define GEMM_DBUF_LOOP32(A_, B_, K_)                                          \
  f32x4 zero4 = {0.f, 0.f, 0.f, 0.f};                                         \
  f32x4 acc[4][4];                                                            \
  _Pragma("unroll")                                                           \
  for (int i = 0; i < 4; i++)                                                 \
    _Pragma("unroll")                                                         \
    for (int j = 0; j < 4; j++) acc[i][j] = zero4;                            \
  const int u0_ = t * 8, u1_ = t * 8 + 2048;                                  \
  const int sr0 = u0_ >> 5, sc0 = ((t & 3) ^ ((sr0 >> 1) & 3));               \
  const int sr1 = u1_ >> 5, sc1 = ((t & 3) ^ ((sr1 >> 1) & 3));               \
  const int nt_ = K_ / 32;                                                    \
  {                                                                           \
    gld_lds16(A_ + (size_t)(m0 + sr0) * K_ + sc0 * 8, &As[0][u0_]);           \
    gld_lds16(A_ + (size_t)(m0 + sr1) * K_ + sc1 * 8, &As[0][u1_]);           \
    gld_lds16(B_ + (size_t)(n0 + sr0) * K_ + sc0 * 8, &Bs[0][u0_]);           \
    gld_lds16(B_ + (size_t)(n0 + sr1) * K_ + sc1 * 8, &Bs[0][u1_]);           \
  }                                                                           \
  for (int kt = 0; kt < nt_; ++kt) {                                          \
    const int buf = kt & 1;                                                   \
    __syncthreads();                                                          \
    if (kt + 1 < nt_) {                                                       \
      const int k0 = (kt + 1) * 32;                                           \
      gld_lds16(A_ + (size_t)(m0 + sr0) * K_ + k0 + sc0 * 8, &As[buf^1][u0_]);\
      gld_lds16(A_ + (size_t)(m0 + sr1) * K_ + k0 + sc1 * 8, &As[buf^1][u1_]);\
      gld_lds16(B_ + (size_t)(n0 + sr0) * K_ + k0 + sc0 * 8, &Bs[buf^1][u0_]);\
      gld_lds16(B_ + (size_t)(n0 + sr1) * K_ + k0 + sc1 * 8, &Bs[buf^1][u1_]);\
    }                                                                         \
    bf16x8 af[4], bfr[4];                                                     \
    _Pragma("unroll")                                                         \
    for (int mi = 0; mi < 4; mi++) {                                          \
      const int row = wm + mi * 16 + ln;                                      \
      af[mi] = *reinterpret_cast<const bf16x8*>(                              \
          &As[buf][row * 32 + ((q ^ ((row >> 1) & 3))) * 8]);                 \
    }                                                                         \
    _Pragma("unroll")                                                         \
    for (int ni = 0; ni < 4; ni++) {                                          \
      const int row = wn + ni * 16 + ln;                                      \
      bfr[ni] = *reinterpret_cast<const bf16x8*>(                             \
          &Bs[buf][row * 32 + ((q ^ ((row >> 1) & 3))) * 8]);                 \
    }                                                                         \
    _Pragma("unroll")                                                         \
    for (int mi = 0; mi < 4; mi++)                                            \
      _Pragma("unroll")                                                       \
      for (int ni = 0; ni < 4; ni++)                                          \
        acc[mi][ni] = __builtin_amdgcn_mfma_f32_16x16x32_bf16(                \
            af[mi], bfr[ni], acc[mi][ni], 0, 0, 0);                           \
  }

// BK=64 dbuf (rows 128B = 8 chunks; chunk ^= row&7) — r8/r11-verified
#define GEMM_DBUF_LOOP64(A_, B_, K_)                                          \
  f32x4 zero4 = {0.f, 0.f, 0.f, 0.f};                                         \
  f32x4 acc[4][4];                                                            \
  _Pragma("unroll")                                                           \
  for (int i = 0; i < 4; i++)                                                 \
    _Pragma("unroll")                                                         \
    for (int j = 0; j < 4; j++) acc[i][j] = zero4;                            \
  {                                                                           \
    _Pragma("unroll")                                                         \
    for (int i = 0; i < 4; i++) {                                             \
      const int u = t * 8 + i * 2048;                                         \
      const int row = u >> 6;                                                 \
      const int c = ((u >> 3) & 7) ^ (row & 7);                               \
      gld_lds16(A_ + (size_t)(m0 + row) * K_ + c * 8, &As[0][u]);             \
      gld_lds16(B_ + (size_t)(n0 + row) * K_ + c * 8, &Bs[0][u]);             \
    }                                                                         \
  }                                                                           \
  for (int kt = 0; kt < K_ / 64; ++kt) {                                      \
    const int buf = kt & 1;                                                   \
    __syncthreads();                                                          \
    if (kt + 1 < K_ / 64) {                                                   \
      const int k0 = (kt + 1) * 64;                                           \
      _Pragma("unroll")                                                       \
      for (int i = 0; i < 4; i++) {                                           \
        const int u = t * 8 + i * 2048;                                       \
        const int row = u >> 6;                                               \
        const int c = ((u >> 3) & 7) ^ (row & 7);                             \
        gld_lds16(A_ + (size_t)(m0 + row) * K_ + k0 + c * 8, &As[buf^1][u]);  \
        gld_lds16(B_ + (size_t)(n0 + row) * K_ + k0 + c * 8, &Bs[buf^1][u]);  \
      }                                                                       \
    }                                                                         \
    _Pragma("unroll")                                                         \
    for (int ks = 0; ks < 2; ++ks) {                                          \
      bf16x8 af[4], bfr[4];                                                   \
      _Pragma("unroll")                                                       \
      for (int mi = 0; mi < 4; mi++) {                                        \
        const int row = wm + mi * 16 + ln;                                    \
        af[mi] = *reinterpret_cast<const bf16x8*>(                            \
            &As[buf][row * 64 + ((ks * 4 + q) ^ (row & 7)) * 8]);             \
      }                                                                       \
      _Pragma("unroll")                                                       \
      for (int ni = 0; ni < 4; ni++) {                                        \
        const int row = wn + ni * 16 + ln;                                    \
        bfr[ni] = *reinterpret_cast<const bf16x8*>(                           \
            &Bs[buf][row * 64 + ((ks * 4 + q) ^ (row & 7)) * 8]);             \
      }                                                                       \
      _Pragma("unroll")                                                       \
      for (int mi = 0; mi < 4; mi++)                                          \
        _Pragma("unroll")                                                     \
        for (int ni = 0; ni < 4; ni++)                                        \
          acc[mi][ni] = __builtin_amdgcn_mfma_f32_16x16x32_bf16(              \
              af[mi], bfr[ni], acc[mi][ni], 0, 0, 0);                         \
    }                                                                         \
  }

// ---------------- fused QKV GEMM + per-head LN(K,Q) + V transpose ----------------
// C[8192][3072] = xb * wb^T; C never hits memory:
//   cols [0,1024):   K-proj -> per-head LN (scale QK_SCALE*LOG2E) -> kn [bh][t][64]
//   cols [1024,2048) Q-proj -> per-head LN (scale QK_SCALE)       -> qn [bh][t][64]
//   cols [2048,3072) V-proj ->                                       vt [bh][64][2048]
// XCD-affine remap (grid 24x64): per-XCD resident panels ~4MB = its L2.
__global__ __launch_bounds__(256, 2) void gemm_kqv(
    const bf16* __restrict__ A, const bf16* __restrict__ Bm,
    bf16* __restrict__ kn, bf16* __restrict__ qn, bf16* __restrict__ vt,
    const float* __restrict__ kg, const float* __restrict__ kb,
    const float* __restrict__ qg, const float* __restrict__ qb)
{
  __shared__ __align__(16) bf16 As[2][128 * 32];
  __shared__ __align__(16) bf16 Bs[2][128 * 32];

  const int t    = threadIdx.x;
  const int lane = t & 63;
  const int wave = t >> 6;
  const int q    = lane >> 4;
  const int ln   = lane & 15;

  const int lid = (int)blockIdx.y * (int)gridDim.x + (int)blockIdx.x;
  const int xcd = lid & 7;
  const int nn  = lid >> 3;
  const int bxr = nn >> 3;                 // [0, 24)
  const int byr = (xcd << 3) | (nn & 7);   // [0, 64)
  const int m0  = byr * 128;
  const int n0  = bxr * 128;

  const int wm = (wave >> 1) * 64;
  const int wn = (wave & 1) * 64;

  GEMM_DBUF_LOOP32(A, Bm, EMB)

  // ---- epilogue (unchanged from round 6, verified) ----
  const int sec = n0 >> 10;                 // 0=K, 1=Q, 2=V
  const int cb  = (n0 & 1023) + wn;         // col within projection
  const int h   = cb >> 6;                  // head
  const int R0  = m0 + wm;

  if (sec == 2) {
    // V: write transposed [bh][d][t]; lane holds 4 consecutive t at fixed d
#pragma unroll
    for (int mi = 0; mi < 4; mi++) {
      const int R = R0 + mi * 16 + q * 4;
      const int b = R >> 11, tt = R & 2047;
#pragma unroll
      for (int ni = 0; ni < 4; ni++) {
        const int d = ni * 16 + ln;
        bf16x4 o4 = { (bf16)acc[mi][ni][0], (bf16)acc[mi][ni][1],
                      (bf16)acc[mi][ni][2], (bf16)acc[mi][ni][3] };
        *reinterpret_cast<bf16x4*>(
            &vt[((size_t)(b * HEADS + h) * HD + d) * SEQ + tt]) = o4;
      }
    }
  } else {
    const float scale = sec ? QK_SCALE : (QK_SCALE * LOG2E);
    const float* gp = sec ? qg : kg;
    const float* bp = sec ? qb : kb;
    bf16* outp = sec ? qn : kn;
    float gv[4], bv[4];
#pragma unroll
    for (int ni = 0; ni < 4; ni++) {
      gv[ni] = gp[ni * 16 + ln];
      bv[ni] = bp[ni * 16 + ln] * scale;
    }
#pragma unroll
    for (int mi = 0; mi < 4; mi++) {
#pragma unroll
      for (int r = 0; r < 4; r++) {
        const float x0 = acc[mi][0][r], x1 = acc[mi][1][r];
        const float x2 = acc[mi][2][r], x3 = acc[mi][3][r];
        float s  = (x0 + x1) + (x2 + x3);
        float s2 = (x0 * x0 + x1 * x1) + (x2 * x2 + x3 * x3);
#pragma unroll
        for (int mm = 1; mm < 16; mm <<= 1) {
          s  += __shfl_xor(s,  mm, 64);
          s2 += __shfl_xor(s2, mm, 64);
        }
        const float mean = s * (1.f / 64.f);
        const float rs = rsqrtf(s2 * (1.f / 64.f) - mean * mean + LNEPS) * scale;
        const int R = R0 + mi * 16 + q * 4 + r;
        const int b = R >> 11, tt = R & 2047;
        const size_t o = ((size_t)(b * HEADS + h) * SEQ + tt) * HD + ln;
#pragma unroll
        for (int ni = 0; ni < 4; ni++)
          outp[o + ni * 16] = (bf16)((acc[mi][ni][r] - mean) * rs * gv[ni] + bv[ni]);
      }
    }
  }
}

// ---------------- output-proj GEMM: out[M][N] = A[M][K] * B[N][K]^T + bias ----------------
// r11 config restored (best measured): BK=64 dbuf, 256 thr, launch_bounds(256,2).
// r12's 512-thr variant regressed: at 2 blocks/CU it adds no residency, only
// coarsens barrier coupling (8 waves stall together with 1 covering block).
__global__ __launch_bounds__(256, 2) void gemm_out(
    const bf16* __restrict__ A, const bf16* __restrict__ Bm,
    float* __restrict__ Cf, const float* __restrict__ bias, int N)
{
  __shared__ __align__(16) bf16 As[2][128 * 64];
  __shared__ __align__(16) bf16 Bs[2][128 * 64];

  const int t    = threadIdx.x;
  const int lane = t & 63;
  const int wave = t >> 6;
  const int q    = lane >> 4;
  const int ln   = lane & 15;

  const int lid = (int)blockIdx.y * (int)gridDim.x + (int)blockIdx.x;
  const int xcd = lid & 7;
  const int nn  = lid >> 3;
  const int bxr = nn >> 3;                 // [0, gridDim.x)
  const int byr = (xcd << 3) | (nn & 7);   // [0, 64)
  const int m0  = byr * 128;
  const int n0  = bxr * 128;

  const int wm = (wave >> 1) * 64;
  const int wn = (wave & 1) * 64;

  GEMM_DBUF_LOOP64(A, Bm, EMB)

#pragma unroll
  for (int mi = 0; mi < 4; mi++) {
#pragma unroll
    for (int ni = 0; ni < 4; ni++) {
#pragma unroll
      for (int r = 0; r < 4; r++) {
        int row = m0 + wm + mi * 16 + q * 4 + r;
        int col = n0 + wn + ni * 16 + ln;
        Cf[(size_t)row * N + col] = acc[mi][ni][r] + bias[col];
      }
    }
  }
}

// ---------------- flash attention (causal), S^T form, QBLK=128 ----------------
// ROUND-13 CHANGE: 512 blocks x 512 thr = 8 waves x 16 Q rows (QBLK=128).
// Mechanism: each staged 8KB K/V tile now feeds 8 waves (was 4) -> staging
// instr/traffic per wave HALVED (1 K + 1 V chunk per thread); per-block
// barrier chain halves (34 uniform steps, pairing bxi <-> 15-bxi). All
// verified components unchanged: Ks/Vs layouts, both-sides swizzles, slab
// math, causal mask, fixed-max softmax, epilogue. Residency: 2 blocks/CU x
// 8 waves = 16 waves/CU (same as before). XCD decode: xcd=id&7, bh=(id>>6)*8
// +xcd -> all 8 blocks of a bh on ONE XCD; 8 bhs x 512KB = 4MB = its L2.
__global__ __launch_bounds__(512, 4) void attn(
    const bf16* __restrict__ Qn, const bf16* __restrict__ Kn, const bf16* __restrict__ Vt,
    bf16* __restrict__ O)
{
  __shared__ __align__(16) bf16 Ks[2][64 * 64];   // [j][d]
  __shared__ __align__(16) bf16 Vs[2][64 * 64];   // [d][j]

  const int id = blockIdx.x;                      // 512 blocks
  const int xcd = id & 7;
  const int bxi = (id >> 3) & 7;                  // 0..7
  const int bh  = ((id >> 6) << 3) | xcd;         // 0..63, bh&7 == xcd
  const int t = threadIdx.x, wave = t >> 6, lane = t & 63;
  const int q = lane >> 4, ln = lane & 15;
  const int b = bh >> 4, h = bh & 15;

  // staging: 1 chunk of 16B per tensor per thread (512 thr x 16B = 8KB tile)
  const int u0 = t * 8;
  const int kr0 = u0 >> 6, kc0 = ((u0 >> 3) & 7) ^ (kr0 & 7);
  const int vd0 = u0 >> 6, vc0 = ((u0 >> 3) & 7) ^ (vd0 & 7);
  const bf16* Kb = Kn + (size_t)bh * SEQ * HD;
  const bf16* Vb = Vt + (size_t)bh * HD * SEQ;

  f32x4 zero4 = {0.f, 0.f, 0.f, 0.f};

  for (int pass = 0; pass < 2; ++pass) {
    const int itile = pass ? (15 - bxi) : bxi;    // 128-row strip index
    const int qbase = itile * 128 + wave * 16;

    // Q fragments (B-operand of S^T mfma): Q[i=qbase+ln][d=ks*32+q*8 ..+8]
    const bf16* qp = Qn + ((size_t)bh * SEQ + qbase + ln) * HD + q * 8;
    bf16x8 qf0 = *reinterpret_cast<const bf16x8*>(qp);
    bf16x8 qf1 = *reinterpret_cast<const bf16x8*>(qp + 32);

    float lrow = 0.f;
    f32x4 oacc[4];                          // [md] tiles of O^T[d][i]
#pragma unroll
    for (int md = 0; md < 4; md++) oacc[md] = zero4;

    const int nj = 2 * itile + 2;           // 64-j tiles covering 0..itile*128+127

    __syncthreads();                        // prior pass reads done before overwrite
    {                                       // prologue: stage jt=0 into buf 0
      gld_lds16(Kb + (size_t)kr0 * HD + kc0 * 8, &Ks[0][u0]);
      gld_lds16(Vb + (size_t)vd0 * SEQ + vc0 * 8, &Vs[0][u0]);
    }

    for (int jt = 0; jt < nj; ++jt) {
      const int buf = jt & 1;
      const int j0 = jt * 64;
      __syncthreads();                      // buf staged & visible; buf^1 reads drained
      if (jt + 1 < nj) {                    // prefetch next tile into other buffer
        const int jn = j0 + 64;
        gld_lds16(Kb + (size_t)(jn + kr0) * HD + kc0 * 8, &Ks[buf ^ 1][u0]);
        gld_lds16(Vb + (size_t)vd0 * SEQ + jn + vc0 * 8, &Vs[buf ^ 1][u0]);
      }

#pragma unroll
      for (int jb = 0; jb < 4; ++jb) {
        const int jslab = j0 + jb * 16;
        if (jslab <= qbase + 15) {          // slab has unmasked elems for this wave
          const int rowj = jb * 16 + ln;
          bf16x8 kf0 = *reinterpret_cast<const bf16x8*>(
              &Ks[buf][rowj * 64 + ((q)     ^ (rowj & 7)) * 8]);
          bf16x8 kf1 = *reinterpret_cast<const bf16x8*>(
              &Ks[buf][rowj * 64 + ((4 + q) ^ (rowj & 7)) * 8]);
          f32x4 z = zero4;
          z = __builtin_amdgcn_mfma_f32_16x16x32_bf16(kf0, qf0, z, 0, 0, 0);
          z = __builtin_amdgcn_mfma_f32_16x16x32_bf16(kf1, qf1, z, 0, 0, 0);
          // z[r] = S^T[j = jslab+q*4+r][i = qbase+ln]
          if (jslab + 15 > qbase) {         // partial slab: mask
#pragma unroll
            for (int r = 0; r < 4; r++) {
              int jj = jslab + q * 4 + r;
              int ii = qbase + ln;
              if (jj > ii) z[r] = -1.0e30f;
            }
          }
          // fixed-max softmax (|s*log2e| <= 2.9 after per-head LN): p = 2^s
          float p0 = exp2f(z[0]), p1 = exp2f(z[1]), p2 = exp2f(z[2]), p3 = exp2f(z[3]);
          lrow += (p0 + p1) + (p2 + p3);
          bf16x4 pk = { (bf16)p0, (bf16)p1, (bf16)p2, (bf16)p3 };   // B-frag (k=j, n=i)

          // O^T += V^T * P^T for this 16-j slab
#pragma unroll
          for (int md = 0; md < 4; md++) {
            const int rowd = md * 16 + ln;
            const bf16* vp = &Vs[buf][rowd * 64 +
                (((jb * 2 + (q >> 1)) ^ (rowd & 7)) * 8) + (q & 1) * 4];
            bf16x4 vf = *reinterpret_cast<const bf16x4*>(vp);
            oacc[md] = mfma_pv(vf, pk, oacc[md]);
          }
        }
      }
    }

    // epilogue: reduce l over the 4 quads holding each column i, normalize, store
    float s = lrow;
    s += __shfl_xor(s, 16, 64);
    s += __shfl_xor(s, 32, 64);
    const float inv = 1.f / s;
    const int row = qbase + ln;
#pragma unroll
    for (int md = 0; md < 4; md++) {
      bf16x4 o4 = { (bf16)(oacc[md][0] * inv), (bf16)(oacc[md][1] * inv),
                    (bf16)(oacc[md][2] * inv), (bf16)(oacc[md][3] * inv) };
      int col = h * HD + md * 16 + q * 4;    // 4 consecutive d
      *reinterpret_cast<bf16x4*>(&O[(size_t)(b * SEQ + row) * EMB + col]) = o4;
    }
  }
}

// ---------------- launch ----------------
extern "C" void kernel_launch(void* const* d_in, const int* in_sizes, int n_in,
                              void* d_out, int out_size, void* d_ws, size_t ws_size,
                              hipStream_t stream)
{
  const float* x   = (const float*)d_in[0];
  const float* Wk  = (const float*)d_in[1];
  const float* Wq  = (const float*)d_in[2];
  const float* Wv  = (const float*)d_in[3];
  const float* Wo  = (const float*)d_in[4];
  const float* bo  = (const float*)d_in[5];
  const float* klg = (const float*)d_in[6];
  const float* klb = (const float*)d_in[7];
  const float* qlg = (const float*)d_in[8];
  const float* qlb = (const float*)d_in[9];
  float* out = (float*)d_out;

  char* ws = (char*)d_ws;
  const size_t OFF_XB  = 0;
  const size_t OFF_WB  = OFF_XB  + (size_t)BT * EMB * 2;
  const size_t OFF_KQV = OFF_WB  + (size_t)4 * EMB * EMB * 2;
  const size_t OFF_KN  = OFF_KQV + (size_t)BT * 3 * EMB * 2;
  const size_t OFF_QN  = OFF_KN  + (size_t)BT * EMB * 2;
  const size_t OFF_VT  = OFF_QN  + (size_t)BT * EMB * 2;
  const size_t OFF_END = OFF_VT  + (size_t)BT * EMB * 2;
  if (ws_size < OFF_END) return;

  bf16* xb   = (bf16*)(ws + OFF_XB);
  bf16* wb   = (bf16*)(ws + OFF_WB);
  bf16* kn   = (bf16*)(ws + OFF_KN);
  bf16* qn   = (bf16*)(ws + OFF_QN);
  bf16* vt   = (bf16*)(ws + OFF_VT);
  bf16* ob   = (bf16*)(ws + OFF_KQV);    // attn output (KQV region unused otherwise)

  cvt_all<<<12288, 256, 0, stream>>>(x, Wk, Wq, Wv, Wo, xb, wb);

  gemm_kqv<<<dim3(3 * EMB / 128, BT / 128), 256, 0, stream>>>(
      xb, wb, kn, qn, vt, klg, klb, qlg, qlb);

  attn<<<dim3(8 * BATCH * HEADS), 512, 0, stream>>>(qn, kn, vt, ob);

  gemm_out<<<dim3(EMB / 128, BT / 128), 256, 0, stream>>>(
      ob, wb + (size_t)3 * EMB * EMB, out, bo, EMB);
}